// Round 7
// baseline (77.082 us; speedup 1.0000x reference)
//
#include <hip/hip_runtime.h>

// Voxelizer3D: out[f][z][y][x] = sum over masked atoms (all coords != 0) whose
// center cell is within Chebyshev distance 1 of (x,y,z), of feat[a][f].
// v7: 4-dispatch bucket pipeline; accum parallelized over (cell, feature).
//   minmax_p (partials + zero counts) -> scatter_bucket (fused cell+count+place)
//   -> accum[(cell,f) threads, 8-deep MLP] -> conv (rolling-z box conv).

constexpr int VOL   = 48;
constexpr int FEATD = 19;
constexpr int VOL3  = VOL * VOL * VOL;      // 110592
constexpr int CAP   = 128;                  // bucket capacity per cell
constexpr int OVCAP = 8192;                 // overflow list capacity (cold)
constexpr int NMB   = 64;                   // minmax partial blocks
constexpr int SCB   = 256;
constexpr int NSB   = VOL3 / SCB;           // 432
constexpr int ZK    = 4;                    // z outputs per conv thread

__device__ __forceinline__ unsigned fkey(float f) {
    unsigned u = __float_as_uint(f);
    return (u & 0x80000000u) ? ~u : (u | 0x80000000u);
}
__device__ __forceinline__ float funkey(unsigned k) {
    unsigned u = (k & 0x80000000u) ? (k & 0x7fffffffu) : ~k;
    return __uint_as_float(u);
}

// ---- K1: per-block min/max partials; zero counts + ovf counter ----
__global__ __launch_bounds__(1024) void vox_minmax_p(const float* __restrict__ xyz,
                                                     int n, unsigned* __restrict__ pb,
                                                     unsigned* __restrict__ counts,
                                                     unsigned* __restrict__ ovf_cnt) {
    int gid = blockIdx.x * blockDim.x + threadIdx.x;
    for (int j = gid; j < VOL3; j += gridDim.x * blockDim.x) counts[j] = 0u;
    if (gid == 0) *ovf_cnt = 0u;

    __shared__ unsigned smin[16][3], smax[16][3];
    unsigned kmin[3] = {~0u, ~0u, ~0u};
    unsigned kmax[3] = {0u, 0u, 0u};
    const int nq = n >> 2;
    const float4* p4 = (const float4*)xyz;
    for (int q = gid; q < nq; q += gridDim.x * blockDim.x) {
        float4 v0 = p4[3 * q], v1 = p4[3 * q + 1], v2 = p4[3 * q + 2];
        float ax[4] = {v0.x, v0.w, v1.z, v2.y};
        float ay[4] = {v0.y, v1.x, v1.w, v2.z};
        float az[4] = {v0.z, v1.y, v2.x, v2.w};
        #pragma unroll
        for (int k = 0; k < 4; k++) {
            if (ax[k] != 0.f && ay[k] != 0.f && az[k] != 0.f) {
                unsigned kk[3] = {fkey(ax[k]), fkey(ay[k]), fkey(az[k])};
                #pragma unroll
                for (int c = 0; c < 3; c++) {
                    kmin[c] = kmin[c] < kk[c] ? kmin[c] : kk[c];
                    kmax[c] = kmax[c] > kk[c] ? kmax[c] : kk[c];
                }
            }
        }
    }
    for (int i = (nq << 2) + gid; i < n; i += gridDim.x * blockDim.x) {
        float x = xyz[3 * i], y = xyz[3 * i + 1], z = xyz[3 * i + 2];
        if (x != 0.f && y != 0.f && z != 0.f) {
            unsigned kk[3] = {fkey(x), fkey(y), fkey(z)};
            #pragma unroll
            for (int c = 0; c < 3; c++) {
                kmin[c] = kmin[c] < kk[c] ? kmin[c] : kk[c];
                kmax[c] = kmax[c] > kk[c] ? kmax[c] : kk[c];
            }
        }
    }
    #pragma unroll
    for (int o = 32; o; o >>= 1) {
        #pragma unroll
        for (int c = 0; c < 3; c++) {
            unsigned omin = __shfl_xor(kmin[c], o, 64);
            unsigned omax = __shfl_xor(kmax[c], o, 64);
            kmin[c] = kmin[c] < omin ? kmin[c] : omin;
            kmax[c] = kmax[c] > omax ? kmax[c] : omax;
        }
    }
    int wave = threadIdx.x >> 6;
    if ((threadIdx.x & 63) == 0) {
        #pragma unroll
        for (int c = 0; c < 3; c++) { smin[wave][c] = kmin[c]; smax[wave][c] = kmax[c]; }
    }
    __syncthreads();
    if (threadIdx.x == 0) {
        int nw = blockDim.x >> 6;
        #pragma unroll
        for (int c = 0; c < 3; c++) { kmin[c] = smin[0][c]; kmax[c] = smax[0][c]; }
        for (int w = 1; w < nw; w++) {
            #pragma unroll
            for (int c = 0; c < 3; c++) {
                kmin[c] = kmin[c] < smin[w][c] ? kmin[c] : smin[w][c];
                kmax[c] = kmax[c] > smax[w][c] ? kmax[c] : smax[w][c];
            }
        }
        #pragma unroll
        for (int c = 0; c < 3; c++) {
            pb[blockIdx.x * 6 + c]     = kmin[c];
            pb[blockIdx.x * 6 + 3 + c] = kmax[c];
        }
    }
}

// reduce the NMB partials -> 6 floats, broadcast via LDS (called inside kernels)
__device__ __forceinline__ void reduce_keys(const unsigned* __restrict__ pb,
                                            float* __restrict__ sm) {
    if (threadIdx.x < 64) {
        unsigned mn[3], mx[3];
        int t = threadIdx.x;
        bool live = t < NMB;
        #pragma unroll
        for (int c = 0; c < 3; c++) {
            mn[c] = live ? pb[t * 6 + c]     : ~0u;
            mx[c] = live ? pb[t * 6 + 3 + c] : 0u;
        }
        #pragma unroll
        for (int o = 32; o; o >>= 1) {
            #pragma unroll
            for (int c = 0; c < 3; c++) {
                unsigned omin = __shfl_xor(mn[c], o, 64);
                unsigned omax = __shfl_xor(mx[c], o, 64);
                mn[c] = mn[c] < omin ? mn[c] : omin;
                mx[c] = mx[c] > omax ? mx[c] : omax;
            }
        }
        if (t == 0) {
            #pragma unroll
            for (int c = 0; c < 3; c++) { sm[c] = funkey(mn[c]); sm[3 + c] = funkey(mx[c]); }
        }
    }
    __syncthreads();
}

// ---- K2: fused cell-compute + count + bucket-place (4 atoms/thread) ----
__global__ __launch_bounds__(SCB) void vox_scatter(const float* __restrict__ xyz, int n,
                                                   const unsigned* __restrict__ pb,
                                                   unsigned* __restrict__ counts,
                                                   unsigned* __restrict__ bucket,
                                                   unsigned* __restrict__ ovf,
                                                   unsigned* __restrict__ ovf_cnt) {
    __shared__ float sm[6];
    reduce_keys(pb, sm);
    const float mnx = sm[0], mny = sm[1], mnz = sm[2];
    const float mxx = sm[3], mxy = sm[4], mxz = sm[5];

    int q = blockIdx.x * blockDim.x + threadIdx.x;
    int i0 = q * 4;
    if (i0 >= n) return;
    float ax[4], ay[4], az[4];
    int cnt4 = 4;
    if (i0 + 4 <= n) {
        const float4* p4 = (const float4*)(xyz + (size_t)i0 * 3);
        float4 v0 = p4[0], v1 = p4[1], v2 = p4[2];
        ax[0]=v0.x; ax[1]=v0.w; ax[2]=v1.z; ax[3]=v2.y;
        ay[0]=v0.y; ay[1]=v1.x; ay[2]=v1.w; ay[3]=v2.z;
        az[0]=v0.z; az[1]=v1.y; az[2]=v2.x; az[3]=v2.w;
    } else {
        cnt4 = n - i0;
        for (int k = 0; k < cnt4; k++) {
            ax[k] = xyz[3 * (i0 + k)]; ay[k] = xyz[3 * (i0 + k) + 1]; az[k] = xyz[3 * (i0 + k) + 2];
        }
    }
    #pragma unroll
    for (int k = 0; k < 4; k++) {
        if (k >= cnt4) break;
        if (ax[k] == 0.f || ay[k] == 0.f || az[k] == 0.f) continue;
        // exact op-order of reference: (x - min) / (max - min) * 47, f32, trunc
        int cx = (int)((ax[k] - mnx) / (mxx - mnx) * 47.0f);
        int cy = (int)((ay[k] - mny) / (mxy - mny) * 47.0f);
        int cz = (int)((az[k] - mnz) / (mxz - mnz) * 47.0f);
        unsigned cell = (unsigned)((cz * VOL + cy) * VOL + cx);
        unsigned slot = atomicAdd(&counts[cell], 1u);
        if (slot < CAP) {
            bucket[(size_t)cell * CAP + slot] = (unsigned)(i0 + k);
        } else {
            unsigned j = atomicAdd(ovf_cnt, 1u);
            if (j < OVCAP) { ovf[2 * j] = cell; ovf[2 * j + 1] = (unsigned)(i0 + k); }
        }
    }
}

// ---- K3: accumulation, one thread per (cell, feature), 8-deep MLP ----
__global__ __launch_bounds__(SCB) void vox_accum(const unsigned* __restrict__ bucket,
                                                 const unsigned* __restrict__ counts,
                                                 const unsigned* __restrict__ ovf,
                                                 const unsigned* __restrict__ ovf_cnt,
                                                 const float* __restrict__ feat,
                                                 float* __restrict__ center) {
    int cell = blockIdx.x * SCB + threadIdx.x;
    int f = blockIdx.y;
    unsigned cnt = counts[cell];
    unsigned use = cnt < CAP ? cnt : CAP;
    const unsigned* b = bucket + (size_t)cell * CAP;
    float acc = 0.f;
    unsigned k = 0;
    while (k < use) {
        unsigned m = use - k; if (m > 8) m = 8;
        unsigned idx[8];
        #pragma unroll
        for (int j = 0; j < 8; j++) idx[j] = b[(k + j) < CAP ? (k + j) : (CAP - 1)];
        #pragma unroll
        for (int j = 0; j < 8; j++)
            if ((unsigned)j < m) acc += feat[(size_t)idx[j] * FEATD + f];
        k += m;
    }
    if (cnt > CAP) {   // cold overflow merge (never taken for this data)
        unsigned no = *ovf_cnt; if (no > OVCAP) no = OVCAP;
        for (unsigned i = 0; i < no; i++)
            if (ovf[2 * i] == (unsigned)cell)
                acc += feat[(size_t)ovf[2 * i + 1] * FEATD + f];
    }
    center[(size_t)f * VOL3 + cell] = acc;
}

// ---- K4: 3x3x3 box conv; each thread does ZK z-outputs (rolling planes) ----
__global__ void vox_conv(const float* __restrict__ center, float* __restrict__ out) {
    int idx = blockIdx.x * blockDim.x + threadIdx.x;
    const int NT = FEATD * (VOL / ZK) * VOL * VOL;
    if (idx >= NT) return;
    int x = idx % VOL;
    int t = idx / VOL;
    int y = t % VOL;  t /= VOL;
    int zb = t % (VOL / ZK);
    int f = t / (VOL / ZK);
    const float* cf = center + (size_t)f * VOL3;

    int ylo = (y > 0) ? y - 1 : 0, yhi = (y < VOL - 1) ? y + 1 : VOL - 1;
    int xlo = (x > 0) ? x - 1 : 0, xhi = (x < VOL - 1) ? x + 1 : VOL - 1;
    auto psum = [&](int zz) -> float {
        if ((unsigned)zz >= (unsigned)VOL) return 0.f;
        float s = 0.f;
        for (int yy = ylo; yy <= yhi; yy++) {
            const float* row = cf + (zz * VOL + yy) * VOL;
            for (int xx = xlo; xx <= xhi; xx++) s += row[xx];
        }
        return s;
    };

    int z0 = zb * ZK;
    float Pm = psum(z0 - 1), Pc = psum(z0);
    #pragma unroll
    for (int k = 0; k < ZK; k++) {
        float Pn = psum(z0 + k + 1);
        out[(((size_t)f * VOL + (z0 + k)) * VOL + y) * VOL + x] = Pm + Pc + Pn;
        Pm = Pc; Pc = Pn;
    }
}

// ---- fallback path (ws too small): keys reduce + direct scatter + flat conv ----
__global__ void vox_keys(const unsigned* __restrict__ pb, unsigned* __restrict__ keys) {
    __shared__ float sm[6];
    reduce_keys(pb, sm);
    if (threadIdx.x < 6) keys[threadIdx.x] = __float_as_uint(sm[threadIdx.x]);
}
__global__ void vox_scatter_lin(const float* __restrict__ xyz,
                                const float* __restrict__ feat, int n,
                                const unsigned* __restrict__ keys,
                                float* __restrict__ center) {
    int i = blockIdx.x * blockDim.x + threadIdx.x;
    if (i >= n) return;
    float x = xyz[3 * i], y = xyz[3 * i + 1], z = xyz[3 * i + 2];
    if (x == 0.f || y == 0.f || z == 0.f) return;
    float mnx = __uint_as_float(keys[0]), mny = __uint_as_float(keys[1]), mnz = __uint_as_float(keys[2]);
    float mxx = __uint_as_float(keys[3]), mxy = __uint_as_float(keys[4]), mxz = __uint_as_float(keys[5]);
    int cx = (int)((x - mnx) / (mxx - mnx) * 47.0f);
    int cy = (int)((y - mny) / (mxy - mny) * 47.0f);
    int cz = (int)((z - mnz) / (mxz - mnz) * 47.0f);
    int cell = (cz * VOL + cy) * VOL + cx;
    const float* fr = feat + (size_t)i * FEATD;
    #pragma unroll
    for (int f = 0; f < FEATD; f++)
        atomicAdd(&center[f * VOL3 + cell], fr[f]);
}
__global__ void vox_conv_flat(const float* __restrict__ center,
                              float* __restrict__ out, int total) {
    int idx = blockIdx.x * blockDim.x + threadIdx.x;
    if (idx >= total) return;
    int x = idx % VOL;
    int t = idx / VOL;
    int y = t % VOL;  t /= VOL;
    int z = t % VOL;
    int f = t / VOL;
    const float* cf = center + (size_t)f * VOL3;
    float s = 0.f;
    for (int dz = -1; dz <= 1; dz++) {
        int zz = z + dz; if ((unsigned)zz >= (unsigned)VOL) continue;
        for (int dy = -1; dy <= 1; dy++) {
            int yy = y + dy; if ((unsigned)yy >= (unsigned)VOL) continue;
            const float* row = cf + (zz * VOL + yy) * VOL;
            #pragma unroll
            for (int dx = -1; dx <= 1; dx++) {
                int xx = x + dx; if ((unsigned)xx >= (unsigned)VOL) continue;
                s += row[xx];
            }
        }
    }
    out[idx] = s;
}

extern "C" void kernel_launch(void* const* d_in, const int* in_sizes, int n_in,
                              void* d_out, int out_size, void* d_ws, size_t ws_size,
                              hipStream_t stream) {
    const float* xyz  = (const float*)d_in[0];
    const float* feat = (const float*)d_in[1];
    float* out = (float*)d_out;
    int n = in_sizes[0] / 3;

    char* w = (char*)d_ws;
    unsigned* pb      = (unsigned*)w;                        // NMB*6 u32 = 1536 B
    unsigned* ovf_cnt = (unsigned*)(w + 1536);               // 4 B (pad to 2048)
    unsigned* counts  = (unsigned*)(w + 2048);               // VOL3*4 = 442368
    size_t o3 = 2048 + (size_t)VOL3 * 4;                     // 444416 (256-aligned)
    unsigned* bucket  = (unsigned*)(w + o3);                 // VOL3*CAP*4 = 56.6 MB
    size_t o4 = o3 + (size_t)VOL3 * CAP * 4;
    float* center     = (float*)(w + o4);                    // FEATD*VOL3*4 = 8.4 MB
    size_t o5 = o4 + (size_t)FEATD * VOL3 * 4;
    unsigned* ovf     = (unsigned*)(w + o5);                 // 2*OVCAP*4 = 64 KB
    size_t need = o5 + (size_t)2 * OVCAP * 4;

    const int b = SCB;
    int nq = (n + 3) / 4;

    if (ws_size >= need) {
        vox_minmax_p<<<NMB, 1024, 0, stream>>>(xyz, n, pb, counts, ovf_cnt);
        vox_scatter<<<(nq + b - 1) / b, b, 0, stream>>>(xyz, n, pb, counts, bucket, ovf, ovf_cnt);
        dim3 ag(NSB, FEATD);
        vox_accum<<<ag, SCB, 0, stream>>>(bucket, counts, ovf, ovf_cnt, feat, center);
        const int nconv = FEATD * (VOL / ZK) * VOL * VOL;
        vox_conv<<<(nconv + b - 1) / b, b, 0, stream>>>(center, out);
    } else {
        unsigned* keys = (unsigned*)(w + 1536 + 64);
        float* c2 = (float*)(w + 4096);
        vox_minmax_p<<<NMB, 1024, 0, stream>>>(xyz, n, pb, counts, ovf_cnt);
        vox_keys<<<1, 64, 0, stream>>>(pb, keys);
        hipMemsetAsync(c2, 0, (size_t)FEATD * VOL3 * 4, stream);
        vox_scatter_lin<<<(n + b - 1) / b, b, 0, stream>>>(xyz, feat, n, keys, c2);
        const int total = FEATD * VOL3;
        vox_conv_flat<<<(total + b - 1) / b, b, 0, stream>>>(c2, out, total);
    }
}

// Round 8
// 62.152 us; speedup vs baseline: 1.2402x; 1.2402x over previous
//
#include <hip/hip_runtime.h>

// Voxelizer3D: out[f][z][y][x] = sum over masked atoms (all coords != 0) whose
// center cell is within Chebyshev distance 1 of (x,y,z), of feat[a][f].
// v8: 4-dispatch bucket pipeline; accum = wave-per-cell with COALESCED feat
// row reads (19 lanes span one row -> 2 transactions/row instead of 19).
//   minmax_p (partials + zero counts) -> scatter_bucket (fused cell+count+place)
//   -> accum (wave/cell, 6 atoms/round, pipelined) -> conv (rolling-z box conv).

constexpr int VOL   = 48;
constexpr int FEATD = 19;
constexpr int VOL3  = VOL * VOL * VOL;      // 110592
constexpr int CAP   = 128;                  // bucket capacity per cell
constexpr int OVCAP = 8192;                 // overflow list capacity (cold)
constexpr int NMB   = 64;                   // minmax partial blocks
constexpr int SCB   = 256;
constexpr int ZK    = 4;                    // z outputs per conv thread

__device__ __forceinline__ unsigned fkey(float f) {
    unsigned u = __float_as_uint(f);
    return (u & 0x80000000u) ? ~u : (u | 0x80000000u);
}
__device__ __forceinline__ float funkey(unsigned k) {
    unsigned u = (k & 0x80000000u) ? (k & 0x7fffffffu) : ~k;
    return __uint_as_float(u);
}

// ---- K1: per-block min/max partials; zero counts + ovf counter ----
__global__ __launch_bounds__(1024) void vox_minmax_p(const float* __restrict__ xyz,
                                                     int n, unsigned* __restrict__ pb,
                                                     unsigned* __restrict__ counts,
                                                     unsigned* __restrict__ ovf_cnt) {
    int gid = blockIdx.x * blockDim.x + threadIdx.x;
    for (int j = gid; j < VOL3; j += gridDim.x * blockDim.x) counts[j] = 0u;
    if (gid == 0) *ovf_cnt = 0u;

    __shared__ unsigned smin[16][3], smax[16][3];
    unsigned kmin[3] = {~0u, ~0u, ~0u};
    unsigned kmax[3] = {0u, 0u, 0u};
    const int nq = n >> 2;
    const float4* p4 = (const float4*)xyz;
    for (int q = gid; q < nq; q += gridDim.x * blockDim.x) {
        float4 v0 = p4[3 * q], v1 = p4[3 * q + 1], v2 = p4[3 * q + 2];
        float ax[4] = {v0.x, v0.w, v1.z, v2.y};
        float ay[4] = {v0.y, v1.x, v1.w, v2.z};
        float az[4] = {v0.z, v1.y, v2.x, v2.w};
        #pragma unroll
        for (int k = 0; k < 4; k++) {
            if (ax[k] != 0.f && ay[k] != 0.f && az[k] != 0.f) {
                unsigned kk[3] = {fkey(ax[k]), fkey(ay[k]), fkey(az[k])};
                #pragma unroll
                for (int c = 0; c < 3; c++) {
                    kmin[c] = kmin[c] < kk[c] ? kmin[c] : kk[c];
                    kmax[c] = kmax[c] > kk[c] ? kmax[c] : kk[c];
                }
            }
        }
    }
    for (int i = (nq << 2) + gid; i < n; i += gridDim.x * blockDim.x) {
        float x = xyz[3 * i], y = xyz[3 * i + 1], z = xyz[3 * i + 2];
        if (x != 0.f && y != 0.f && z != 0.f) {
            unsigned kk[3] = {fkey(x), fkey(y), fkey(z)};
            #pragma unroll
            for (int c = 0; c < 3; c++) {
                kmin[c] = kmin[c] < kk[c] ? kmin[c] : kk[c];
                kmax[c] = kmax[c] > kk[c] ? kmax[c] : kk[c];
            }
        }
    }
    #pragma unroll
    for (int o = 32; o; o >>= 1) {
        #pragma unroll
        for (int c = 0; c < 3; c++) {
            unsigned omin = __shfl_xor(kmin[c], o, 64);
            unsigned omax = __shfl_xor(kmax[c], o, 64);
            kmin[c] = kmin[c] < omin ? kmin[c] : omin;
            kmax[c] = kmax[c] > omax ? kmax[c] : omax;
        }
    }
    int wave = threadIdx.x >> 6;
    if ((threadIdx.x & 63) == 0) {
        #pragma unroll
        for (int c = 0; c < 3; c++) { smin[wave][c] = kmin[c]; smax[wave][c] = kmax[c]; }
    }
    __syncthreads();
    if (threadIdx.x == 0) {
        int nw = blockDim.x >> 6;
        #pragma unroll
        for (int c = 0; c < 3; c++) { kmin[c] = smin[0][c]; kmax[c] = smax[0][c]; }
        for (int w = 1; w < nw; w++) {
            #pragma unroll
            for (int c = 0; c < 3; c++) {
                kmin[c] = kmin[c] < smin[w][c] ? kmin[c] : smin[w][c];
                kmax[c] = kmax[c] > smax[w][c] ? kmax[c] : smax[w][c];
            }
        }
        #pragma unroll
        for (int c = 0; c < 3; c++) {
            pb[blockIdx.x * 6 + c]     = kmin[c];
            pb[blockIdx.x * 6 + 3 + c] = kmax[c];
        }
    }
}

// reduce the NMB partials -> 6 floats, broadcast via LDS (called inside kernels)
__device__ __forceinline__ void reduce_keys(const unsigned* __restrict__ pb,
                                            float* __restrict__ sm) {
    if (threadIdx.x < 64) {
        unsigned mn[3], mx[3];
        int t = threadIdx.x;
        bool live = t < NMB;
        #pragma unroll
        for (int c = 0; c < 3; c++) {
            mn[c] = live ? pb[t * 6 + c]     : ~0u;
            mx[c] = live ? pb[t * 6 + 3 + c] : 0u;
        }
        #pragma unroll
        for (int o = 32; o; o >>= 1) {
            #pragma unroll
            for (int c = 0; c < 3; c++) {
                unsigned omin = __shfl_xor(mn[c], o, 64);
                unsigned omax = __shfl_xor(mx[c], o, 64);
                mn[c] = mn[c] < omin ? mn[c] : omin;
                mx[c] = mx[c] > omax ? mx[c] : omax;
            }
        }
        if (t == 0) {
            #pragma unroll
            for (int c = 0; c < 3; c++) { sm[c] = funkey(mn[c]); sm[3 + c] = funkey(mx[c]); }
        }
    }
    __syncthreads();
}

// ---- K2: fused cell-compute + count + bucket-place (4 atoms/thread) ----
__global__ __launch_bounds__(SCB) void vox_scatter(const float* __restrict__ xyz, int n,
                                                   const unsigned* __restrict__ pb,
                                                   unsigned* __restrict__ counts,
                                                   unsigned* __restrict__ bucket,
                                                   unsigned* __restrict__ ovf,
                                                   unsigned* __restrict__ ovf_cnt) {
    __shared__ float sm[6];
    reduce_keys(pb, sm);
    const float mnx = sm[0], mny = sm[1], mnz = sm[2];
    const float mxx = sm[3], mxy = sm[4], mxz = sm[5];

    int q = blockIdx.x * blockDim.x + threadIdx.x;
    int i0 = q * 4;
    if (i0 >= n) return;
    float ax[4], ay[4], az[4];
    int cnt4 = 4;
    if (i0 + 4 <= n) {
        const float4* p4 = (const float4*)(xyz + (size_t)i0 * 3);
        float4 v0 = p4[0], v1 = p4[1], v2 = p4[2];
        ax[0]=v0.x; ax[1]=v0.w; ax[2]=v1.z; ax[3]=v2.y;
        ay[0]=v0.y; ay[1]=v1.x; ay[2]=v1.w; ay[3]=v2.z;
        az[0]=v0.z; az[1]=v1.y; az[2]=v2.x; az[3]=v2.w;
    } else {
        cnt4 = n - i0;
        for (int k = 0; k < cnt4; k++) {
            ax[k] = xyz[3 * (i0 + k)]; ay[k] = xyz[3 * (i0 + k) + 1]; az[k] = xyz[3 * (i0 + k) + 2];
        }
    }
    #pragma unroll
    for (int k = 0; k < 4; k++) {
        if (k >= cnt4) break;
        if (ax[k] == 0.f || ay[k] == 0.f || az[k] == 0.f) continue;
        // exact op-order of reference: (x - min) / (max - min) * 47, f32, trunc
        int cx = (int)((ax[k] - mnx) / (mxx - mnx) * 47.0f);
        int cy = (int)((ay[k] - mny) / (mxy - mny) * 47.0f);
        int cz = (int)((az[k] - mnz) / (mxz - mnz) * 47.0f);
        unsigned cell = (unsigned)((cz * VOL + cy) * VOL + cx);
        unsigned slot = atomicAdd(&counts[cell], 1u);
        if (slot < CAP) {
            bucket[(size_t)cell * CAP + slot] = (unsigned)(i0 + k);
        } else {
            unsigned j = atomicAdd(ovf_cnt, 1u);
            if (j < OVCAP) { ovf[2 * j] = cell; ovf[2 * j + 1] = (unsigned)(i0 + k); }
        }
    }
}

// ---- K3: accum, one WAVE per cell; lane = f + 19*j -> coalesced row reads ----
__global__ __launch_bounds__(256) void vox_accum(const unsigned* __restrict__ bucket,
                                                 const unsigned* __restrict__ counts,
                                                 const unsigned* __restrict__ ovf,
                                                 const unsigned* __restrict__ ovf_cnt,
                                                 const float* __restrict__ feat,
                                                 float* __restrict__ center) {
    __shared__ float tile[4][FEATD];
    const int wave = threadIdx.x >> 6;
    const int lane = threadIdx.x & 63;
    const int cell = blockIdx.x * 4 + wave;         // grid.x = VOL3/4
    const int f = lane % FEATD;                     // 0..18
    const int j = lane / FEATD;                     // 0..3 (j==3: idle lanes)
    const bool act = j < 3;

    unsigned cnt = counts[cell];
    unsigned use = cnt < CAP ? cnt : CAP;
    const unsigned* b = bucket + (size_t)cell * CAP;

    float acc = 0.f;
    // software-pipelined: 6 atoms/round (2 per j-group), indices one round ahead
    unsigned idx0 = 0, idx1 = 0;
    bool l0 = act && ((unsigned)j < use);
    bool l1 = act && ((unsigned)(j + 3) < use);
    if (l0) idx0 = b[j];
    if (l1) idx1 = b[j + 3];
    unsigned k = 0;
    while (k < use) {
        unsigned nk = k + 6;
        bool n0 = act && (nk + j < use);
        bool n1 = act && (nk + j + 3 < use);
        unsigned nidx0 = 0, nidx1 = 0;
        if (n0) nidx0 = b[nk + j];
        if (n1) nidx1 = b[nk + j + 3];
        if (l0) acc += feat[(size_t)idx0 * FEATD + f];   // 19 lanes span one row
        if (l1) acc += feat[(size_t)idx1 * FEATD + f];
        k = nk; idx0 = nidx0; idx1 = nidx1; l0 = n0; l1 = n1;
    }
    if (cnt > CAP) {   // cold overflow merge (never taken for this data)
        unsigned no = *ovf_cnt; if (no > OVCAP) no = OVCAP;
        if (lane < FEATD) {
            for (unsigned i = 0; i < no; i++)
                if (ovf[2 * i] == (unsigned)cell)
                    acc += feat[(size_t)ovf[2 * i + 1] * FEATD + f];
        }
    }
    // reduce the 3 j-partials into lanes 0..18
    float a1 = __shfl(acc, lane + FEATD, 64);
    float a2 = __shfl(acc, lane + 2 * FEATD, 64);
    if (lane < FEATD) tile[wave][lane] = acc + a1 + a2;
    __syncthreads();
    // grouped write: 4 consecutive cells per feature -> 16B bursts
    int t = threadIdx.x;
    if (t < 4 * FEATD) {
        int ff = t >> 2, c = t & 3;
        center[(size_t)ff * VOL3 + blockIdx.x * 4 + c] = tile[c][ff];
    }
}

// ---- K4: 3x3x3 box conv; each thread does ZK z-outputs (rolling planes) ----
__global__ void vox_conv(const float* __restrict__ center, float* __restrict__ out) {
    int idx = blockIdx.x * blockDim.x + threadIdx.x;
    const int NT = FEATD * (VOL / ZK) * VOL * VOL;
    if (idx >= NT) return;
    int x = idx % VOL;
    int t = idx / VOL;
    int y = t % VOL;  t /= VOL;
    int zb = t % (VOL / ZK);
    int f = t / (VOL / ZK);
    const float* cf = center + (size_t)f * VOL3;

    int ylo = (y > 0) ? y - 1 : 0, yhi = (y < VOL - 1) ? y + 1 : VOL - 1;
    int xlo = (x > 0) ? x - 1 : 0, xhi = (x < VOL - 1) ? x + 1 : VOL - 1;
    auto psum = [&](int zz) -> float {
        if ((unsigned)zz >= (unsigned)VOL) return 0.f;
        float s = 0.f;
        for (int yy = ylo; yy <= yhi; yy++) {
            const float* row = cf + (zz * VOL + yy) * VOL;
            for (int xx = xlo; xx <= xhi; xx++) s += row[xx];
        }
        return s;
    };

    int z0 = zb * ZK;
    float Pm = psum(z0 - 1), Pc = psum(z0);
    #pragma unroll
    for (int k = 0; k < ZK; k++) {
        float Pn = psum(z0 + k + 1);
        out[(((size_t)f * VOL + (z0 + k)) * VOL + y) * VOL + x] = Pm + Pc + Pn;
        Pm = Pc; Pc = Pn;
    }
}

// ---- fallback path (ws too small): keys reduce + direct scatter + flat conv ----
__global__ void vox_keys(const unsigned* __restrict__ pb, unsigned* __restrict__ keys) {
    __shared__ float sm[6];
    reduce_keys(pb, sm);
    if (threadIdx.x < 6) keys[threadIdx.x] = __float_as_uint(sm[threadIdx.x]);
}
__global__ void vox_scatter_lin(const float* __restrict__ xyz,
                                const float* __restrict__ feat, int n,
                                const unsigned* __restrict__ keys,
                                float* __restrict__ center) {
    int i = blockIdx.x * blockDim.x + threadIdx.x;
    if (i >= n) return;
    float x = xyz[3 * i], y = xyz[3 * i + 1], z = xyz[3 * i + 2];
    if (x == 0.f || y == 0.f || z == 0.f) return;
    float mnx = __uint_as_float(keys[0]), mny = __uint_as_float(keys[1]), mnz = __uint_as_float(keys[2]);
    float mxx = __uint_as_float(keys[3]), mxy = __uint_as_float(keys[4]), mxz = __uint_as_float(keys[5]);
    int cx = (int)((x - mnx) / (mxx - mnx) * 47.0f);
    int cy = (int)((y - mny) / (mxy - mny) * 47.0f);
    int cz = (int)((z - mnz) / (mxz - mnz) * 47.0f);
    int cell = (cz * VOL + cy) * VOL + cx;
    const float* fr = feat + (size_t)i * FEATD;
    #pragma unroll
    for (int f = 0; f < FEATD; f++)
        atomicAdd(&center[f * VOL3 + cell], fr[f]);
}
__global__ void vox_conv_flat(const float* __restrict__ center,
                              float* __restrict__ out, int total) {
    int idx = blockIdx.x * blockDim.x + threadIdx.x;
    if (idx >= total) return;
    int x = idx % VOL;
    int t = idx / VOL;
    int y = t % VOL;  t /= VOL;
    int z = t % VOL;
    int f = t / VOL;
    const float* cf = center + (size_t)f * VOL3;
    float s = 0.f;
    for (int dz = -1; dz <= 1; dz++) {
        int zz = z + dz; if ((unsigned)zz >= (unsigned)VOL) continue;
        for (int dy = -1; dy <= 1; dy++) {
            int yy = y + dy; if ((unsigned)yy >= (unsigned)VOL) continue;
            const float* row = cf + (zz * VOL + yy) * VOL;
            #pragma unroll
            for (int dx = -1; dx <= 1; dx++) {
                int xx = x + dx; if ((unsigned)xx >= (unsigned)VOL) continue;
                s += row[xx];
            }
        }
    }
    out[idx] = s;
}

extern "C" void kernel_launch(void* const* d_in, const int* in_sizes, int n_in,
                              void* d_out, int out_size, void* d_ws, size_t ws_size,
                              hipStream_t stream) {
    const float* xyz  = (const float*)d_in[0];
    const float* feat = (const float*)d_in[1];
    float* out = (float*)d_out;
    int n = in_sizes[0] / 3;

    char* w = (char*)d_ws;
    unsigned* pb      = (unsigned*)w;                        // NMB*6 u32 = 1536 B
    unsigned* ovf_cnt = (unsigned*)(w + 1536);               // 4 B (pad to 2048)
    unsigned* counts  = (unsigned*)(w + 2048);               // VOL3*4 = 442368
    size_t o3 = 2048 + (size_t)VOL3 * 4;                     // 444416 (256-aligned)
    unsigned* bucket  = (unsigned*)(w + o3);                 // VOL3*CAP*4 = 56.6 MB
    size_t o4 = o3 + (size_t)VOL3 * CAP * 4;
    float* center     = (float*)(w + o4);                    // FEATD*VOL3*4 = 8.4 MB
    size_t o5 = o4 + (size_t)FEATD * VOL3 * 4;
    unsigned* ovf     = (unsigned*)(w + o5);                 // 2*OVCAP*4 = 64 KB
    size_t need = o5 + (size_t)2 * OVCAP * 4;

    const int b = SCB;
    int nq = (n + 3) / 4;

    if (ws_size >= need) {
        vox_minmax_p<<<NMB, 1024, 0, stream>>>(xyz, n, pb, counts, ovf_cnt);
        vox_scatter<<<(nq + b - 1) / b, b, 0, stream>>>(xyz, n, pb, counts, bucket, ovf, ovf_cnt);
        vox_accum<<<VOL3 / 4, 256, 0, stream>>>(bucket, counts, ovf, ovf_cnt, feat, center);
        const int nconv = FEATD * (VOL / ZK) * VOL * VOL;
        vox_conv<<<(nconv + b - 1) / b, b, 0, stream>>>(center, out);
    } else {
        unsigned* keys = (unsigned*)(w + 1536 + 64);
        float* c2 = (float*)(w + 4096);
        vox_minmax_p<<<NMB, 1024, 0, stream>>>(xyz, n, pb, counts, ovf_cnt);
        vox_keys<<<1, 64, 0, stream>>>(pb, keys);
        hipMemsetAsync(c2, 0, (size_t)FEATD * VOL3 * 4, stream);
        vox_scatter_lin<<<(n + b - 1) / b, b, 0, stream>>>(xyz, feat, n, keys, c2);
        const int total = FEATD * VOL3;
        vox_conv_flat<<<(total + b - 1) / b, b, 0, stream>>>(c2, out, total);
    }
}